// Round 6
// baseline (130.497 us; speedup 1.0000x reference)
//
#include <hip/hip_runtime.h>
#include <math.h>

#define NROWS 16384
#define NCOLS 4096
#define RPC   128              // rows per chunk
#define NCHUNK (NROWS / RPC)   // 128 blocks

// ---------------------------------------------------------------------------
// Stage 1: per-(row-chunk) partial sums of the 5 stats for ALL columns.
// One 1024-thread block spans the full 4096-col row (thread t owns cols
// 4t..4t+3, float4 = 16 B/lane). Each block streams 128 contiguous rows
// (2x 2 MB). grid = 128 blocks. Stage-1 read BW has been config-invariant
// at ~4.3-4.7 TB/s across rounds 1-5 (8..32 waves/CU, comb vs contiguous,
// 1- vs 2-deep pipelines) = ~95% of the m146 read-dominant reference
// (4.89 TB/s) -> treated as the platform streaming-read ceiling.
// partial layout: [gy][5][NCOLS] floats -> 10 MB total.
// ---------------------------------------------------------------------------
__global__ __launch_bounds__(1024, 8) void stats_partial_kernel(
    const float* __restrict__ preds,
    const float* __restrict__ targets,
    float* __restrict__ partial)
{
    const int col = threadIdx.x * 4;
    const size_t r0 = (size_t)blockIdx.x * RPC;

    const float* __restrict__ pp = preds   + r0 * NCOLS + col;
    const float* __restrict__ tp = targets + r0 * NCOLS + col;

    float4 sp  = {0.f, 0.f, 0.f, 0.f};
    float4 st  = {0.f, 0.f, 0.f, 0.f};
    float4 spp = {0.f, 0.f, 0.f, 0.f};
    float4 stt = {0.f, 0.f, 0.f, 0.f};
    float4 spt = {0.f, 0.f, 0.f, 0.f};

    #pragma unroll 4
    for (int r = 0; r < RPC; ++r) {
        float4 p = *(const float4*)pp;
        float4 t = *(const float4*)tp;
        sp.x  += p.x;        sp.y  += p.y;        sp.z  += p.z;        sp.w  += p.w;
        st.x  += t.x;        st.y  += t.y;        st.z  += t.z;        st.w  += t.w;
        spp.x += p.x * p.x;  spp.y += p.y * p.y;  spp.z += p.z * p.z;  spp.w += p.w * p.w;
        stt.x += t.x * t.x;  stt.y += t.y * t.y;  stt.z += t.z * t.z;  stt.w += t.w * t.w;
        spt.x += p.x * t.x;  spt.y += p.y * t.y;  spt.z += p.z * t.z;  spt.w += p.w * t.w;
        pp += NCOLS;
        tp += NCOLS;
    }

    float* base = partial + ((size_t)blockIdx.x * 5) * NCOLS + col;
    *(float4*)(base + 0 * NCOLS) = sp;
    *(float4*)(base + 1 * NCOLS) = st;
    *(float4*)(base + 2 * NCOLS) = spp;
    *(float4*)(base + 3 * NCOLS) = stt;
    *(float4*)(base + 4 * NCOLS) = spt;
}

// ---------------------------------------------------------------------------
// Stage 2 (final): reduce partials over chunks, per-column pcc/cos, block
// reduction, one atomicAdd per block into d_out (init'd to 0 by memset).
// grid = NCOLS/16 = 256 blocks, 256 threads = 16 cols x 16 chunk-lanes
// (each lane strides 8 of the 128 chunks).
// Each block adds (2/256 - blocksum/NCOLS); total = 2 - mean(pcc+cos).
// ---------------------------------------------------------------------------
__global__ __launch_bounds__(256) void reduce_cols_kernel(
    const float* __restrict__ partial,
    float* __restrict__ out)
{
    const int ci  = threadIdx.x & 15;   // column within block
    const int gi  = threadIdx.x >> 4;   // chunk-lane 0..15
    const int col = blockIdx.x * 16 + ci;

    float s[5] = {0.f, 0.f, 0.f, 0.f, 0.f};
    #pragma unroll
    for (int gy = gi; gy < NCHUNK; gy += 16) {
        const float* base = partial + ((size_t)gy * 5) * NCOLS + col;
        #pragma unroll
        for (int k = 0; k < 5; ++k) s[k] += base[k * NCOLS];
    }

    __shared__ float red[256][5];
    #pragma unroll
    for (int k = 0; k < 5; ++k) red[threadIdx.x][k] = s[k];
    __syncthreads();

    __shared__ float colval[16];
    if (threadIdx.x < 16) {
        float t[5] = {0.f, 0.f, 0.f, 0.f, 0.f};
        for (int g = 0; g < 16; ++g) {
            #pragma unroll
            for (int k = 0; k < 5; ++k) t[k] += red[threadIdx.x + 16 * g][k];
        }
        // t = {sum_p, sum_t, sum_pp, sum_tt, sum_pt}
        const float invN = 1.0f / (float)NROWS;
        float mu_p = t[0] * invN;
        float mu_t = t[1] * invN;
        float var_p = fmaxf(t[2] * invN - mu_p * mu_p, 0.f);
        float var_t = fmaxf(t[3] * invN - mu_t * mu_t, 0.f);
        float cov   = t[4] * invN - mu_p * mu_t;

        float denom = sqrtf(var_p * var_t);
        float pcc = (denom > 0.f) ? (cov / denom) : 0.f;  // NaN -> 0 semantics

        float np_ = fmaxf(sqrtf(t[2]), 1e-8f);
        float nt_ = fmaxf(sqrtf(t[3]), 1e-8f);
        float cs  = t[4] / (np_ * nt_);

        colval[threadIdx.x] = pcc + cs;
    }
    __syncthreads();

    if (threadIdx.x == 0) {
        float b = 0.f;
        #pragma unroll
        for (int i = 0; i < 16; ++i) b += colval[i];
        float contrib = 2.0f / 256.0f - b / (float)NCOLS;
        atomicAdd(out, contrib);
    }
}

extern "C" void kernel_launch(void* const* d_in, const int* in_sizes, int n_in,
                              void* d_out, int out_size, void* d_ws, size_t ws_size,
                              hipStream_t stream) {
    const float* preds   = (const float*)d_in[0];
    const float* targets = (const float*)d_in[1];
    float* out = (float*)d_out;
    float* partial = (float*)d_ws;   // NCHUNK*5*NCOLS*4 = 10 MB (ws ~1 GB)

    hipMemsetAsync(d_out, 0, sizeof(float), stream);

    stats_partial_kernel<<<NCHUNK, 1024, 0, stream>>>(preds, targets, partial);
    reduce_cols_kernel<<<NCOLS / 16, 256, 0, stream>>>(partial, out);
}

// Round 7
// 105.951 us; speedup vs baseline: 1.2317x; 1.2317x over previous
//
#include <hip/hip_runtime.h>
#include <math.h>

#define NROWS 16384
#define NCOLS 4096
#define RPC   128              // rows per chunk
#define NCHUNK (NROWS / RPC)   // 128 row-chunks
#define HALF  (NCOLS / 2)      // 2048 cols per block (float2 per lane)

// ---------------------------------------------------------------------------
// Stage 1: per-(row-chunk) partial sums of the 5 stats.
// grid = (2 col-halves, 128 row-chunks) = 256 blocks = 1/CU (round 6 showed
// 128 blocks leaves half the CUs idle; rounds 1-5 show read BW is otherwise
// config-invariant at ~4.3-4.7 TB/s ~= platform streaming-read ceiling).
// 1024 threads x float2 = 2048 cols per block; 128 contiguous rows.
// partial layout: [gy][5][NCOLS] floats -> 10 MB total.
// Block (0,0) thread 0 zeroes d_out (replaces the memset dispatch; stream
// order guarantees it lands before stage 2's atomics).
// ---------------------------------------------------------------------------
__global__ __launch_bounds__(1024, 8) void stats_partial_kernel(
    const float* __restrict__ preds,
    const float* __restrict__ targets,
    float* __restrict__ partial,
    float* __restrict__ out)
{
    if (blockIdx.x == 0 && blockIdx.y == 0 && threadIdx.x == 0)
        out[0] = 0.0f;

    const int col   = blockIdx.x * HALF + threadIdx.x * 2;
    const size_t r0 = (size_t)blockIdx.y * RPC;

    const float* __restrict__ pp = preds   + r0 * NCOLS + col;
    const float* __restrict__ tp = targets + r0 * NCOLS + col;

    float2 sp  = {0.f, 0.f};
    float2 st  = {0.f, 0.f};
    float2 spp = {0.f, 0.f};
    float2 stt = {0.f, 0.f};
    float2 spt = {0.f, 0.f};

    #pragma unroll 8
    for (int r = 0; r < RPC; ++r) {
        float2 p = *(const float2*)pp;
        float2 t = *(const float2*)tp;
        sp.x  += p.x;        sp.y  += p.y;
        st.x  += t.x;        st.y  += t.y;
        spp.x += p.x * p.x;  spp.y += p.y * p.y;
        stt.x += t.x * t.x;  stt.y += t.y * t.y;
        spt.x += p.x * t.x;  spt.y += p.y * t.y;
        pp += NCOLS;
        tp += NCOLS;
    }

    float* base = partial + ((size_t)blockIdx.y * 5) * NCOLS + col;
    *(float2*)(base + 0 * NCOLS) = sp;
    *(float2*)(base + 1 * NCOLS) = st;
    *(float2*)(base + 2 * NCOLS) = spp;
    *(float2*)(base + 3 * NCOLS) = stt;
    *(float2*)(base + 4 * NCOLS) = spt;
}

// ---------------------------------------------------------------------------
// Stage 2 (final): reduce partials over 128 chunks, per-column pcc/cos,
// block reduction, one atomicAdd per block into d_out.
// grid = NCOLS/16 = 256 blocks, 256 threads = 16 cols x 16 chunk-lanes
// (each lane strides 8 of the 128 chunks).
// Each block adds (2/256 - blocksum/NCOLS); total = 2 - mean(pcc+cos).
// ---------------------------------------------------------------------------
__global__ __launch_bounds__(256) void reduce_cols_kernel(
    const float* __restrict__ partial,
    float* __restrict__ out)
{
    const int ci  = threadIdx.x & 15;   // column within block
    const int gi  = threadIdx.x >> 4;   // chunk-lane 0..15
    const int col = blockIdx.x * 16 + ci;

    float s[5] = {0.f, 0.f, 0.f, 0.f, 0.f};
    #pragma unroll
    for (int gy = gi; gy < NCHUNK; gy += 16) {
        const float* base = partial + ((size_t)gy * 5) * NCOLS + col;
        #pragma unroll
        for (int k = 0; k < 5; ++k) s[k] += base[k * NCOLS];
    }

    __shared__ float red[256][5];
    #pragma unroll
    for (int k = 0; k < 5; ++k) red[threadIdx.x][k] = s[k];
    __syncthreads();

    __shared__ float colval[16];
    if (threadIdx.x < 16) {
        float t[5] = {0.f, 0.f, 0.f, 0.f, 0.f};
        for (int g = 0; g < 16; ++g) {
            #pragma unroll
            for (int k = 0; k < 5; ++k) t[k] += red[threadIdx.x + 16 * g][k];
        }
        // t = {sum_p, sum_t, sum_pp, sum_tt, sum_pt}
        const float invN = 1.0f / (float)NROWS;
        float mu_p = t[0] * invN;
        float mu_t = t[1] * invN;
        float var_p = fmaxf(t[2] * invN - mu_p * mu_p, 0.f);
        float var_t = fmaxf(t[3] * invN - mu_t * mu_t, 0.f);
        float cov   = t[4] * invN - mu_p * mu_t;

        float denom = sqrtf(var_p * var_t);
        float pcc = (denom > 0.f) ? (cov / denom) : 0.f;  // NaN -> 0 semantics

        float np_ = fmaxf(sqrtf(t[2]), 1e-8f);
        float nt_ = fmaxf(sqrtf(t[3]), 1e-8f);
        float cs  = t[4] / (np_ * nt_);

        colval[threadIdx.x] = pcc + cs;
    }
    __syncthreads();

    if (threadIdx.x == 0) {
        float b = 0.f;
        #pragma unroll
        for (int i = 0; i < 16; ++i) b += colval[i];
        float contrib = 2.0f / 256.0f - b / (float)NCOLS;
        atomicAdd(out, contrib);
    }
}

extern "C" void kernel_launch(void* const* d_in, const int* in_sizes, int n_in,
                              void* d_out, int out_size, void* d_ws, size_t ws_size,
                              hipStream_t stream) {
    const float* preds   = (const float*)d_in[0];
    const float* targets = (const float*)d_in[1];
    float* out = (float*)d_out;
    float* partial = (float*)d_ws;   // NCHUNK*5*NCOLS*4 = 10 MB (ws ~1 GB)

    dim3 grid1(2, NCHUNK);
    stats_partial_kernel<<<grid1, 1024, 0, stream>>>(preds, targets, partial, out);
    reduce_cols_kernel<<<NCOLS / 16, 256, 0, stream>>>(partial, out);
}